// Round 13
// baseline (114.404 us; speedup 1.0000x reference)
//
#include <hip/hip_runtime.h>
#include <math.h>

constexpr float WLIM = 5000.0f;
constexpr double RIDGE = 1e-7;

#define G 512             // edge chunks (one block each in k_sort; 2 per thread in k_node3)
#define SBT 512           // k_sort threads per block
#define MAXNB 1024        // max buckets (nN up to 131072)
#define BN 128            // nodes per bucket
#define CAP 5120          // LDS edge capacity per bucket in k_node3 (mean 4096, +16 sigma)
#define EBUF_CAP 6272     // LDS edge capacity per chunk in k_sort (CE <= 6252)

// ---------------- Kernel 1: fused per-chunk {histogram, wave-scan, counting sort, dump} ----
// Block g handles edges [g*CE, min((g+1)*CE, nE)). CE is a multiple of 4 so chunk
// bases stay 16B-aligned. Writes:
//   sorted[g*CE + i]   : chunk's edges grouped by bucket (packed (r&127)<<17 | c)
//   table[b*G + g]     : TRANSPOSED exclusive offset of bucket b within chunk g; row NB = count
__global__ __launch_bounds__(SBT) void k_sort(const int* __restrict__ row,
                                              const int* __restrict__ col,
                                              int* __restrict__ table,
                                              unsigned int* __restrict__ sorted,
                                              int nE, int CE, int NB) {
    __shared__ int h[MAXNB];            // histogram -> cursors
    __shared__ int wt[SBT / 64];
    __shared__ unsigned int ebuf[EBUF_CAP];
    const int g = blockIdx.x, tid = threadIdx.x;
    const int lane = tid & 63, wid = tid >> 6;
    const int s = g * CE;
    const int e_end = min(s + CE, nE);
    const int cnt = max(0, e_end - s);

    for (int i = tid; i < MAXNB; i += SBT) h[i] = 0;
    __syncthreads();
    // pass 1: histogram (LDS int atomics), int4 loads
    {
        const int4* r4p = (const int4*)(row + s);
        int nv = cnt >> 2;
        for (int i = tid; i < nv; i += SBT) {
            int4 r4 = r4p[i];
            atomicAdd(&h[r4.x >> 7], 1);
            atomicAdd(&h[r4.y >> 7], 1);
            atomicAdd(&h[r4.z >> 7], 1);
            atomicAdd(&h[r4.w >> 7], 1);
        }
        for (int i = (nv << 2) + tid; i < cnt; i += SBT)
            atomicAdd(&h[row[s + i] >> 7], 1);
    }
    __syncthreads();
    // wave-shfl scan of h[0..1023], 2 entries/thread (2 barriers total)
    int v0 = h[2 * tid], v1 = h[2 * tid + 1];
    int v = v0 + v1;
    int x = v;
    #pragma unroll
    for (int d = 1; d < 64; d <<= 1) {
        int u = __shfl_up(x, d);
        if (lane >= d) x += u;
    }
    if (lane == 63) wt[wid] = x;
    __syncthreads();
    if (tid < SBT / 64) {
        int w = wt[tid];
        int xx = w;
        #pragma unroll
        for (int d = 1; d < SBT / 64; d <<= 1) {
            int u = __shfl_up(xx, d);
            if (tid >= d) xx += u;
        }
        wt[tid] = xx - w;               // exclusive wave offset
    }
    __syncthreads();
    int base = (x - v) + wt[wid];       // exclusive offset of this thread's pair
    int e0 = base, e1 = base + v0;
    if (2 * tid < NB)     table[(size_t)(2 * tid) * G + g] = e0;
    if (2 * tid + 1 < NB) table[(size_t)(2 * tid + 1) * G + g] = e1;
    if (tid == 0) table[(size_t)NB * G + g] = cnt;
    h[2 * tid] = e0;                    // cursors (own slots; reads completed pre-barrier)
    h[2 * tid + 1] = e1;
    __syncthreads();
    // pass 2: counting sort into LDS (int4 loads, L2-warm)
    {
        const int4* r4p = (const int4*)(row + s);
        const int4* c4p = (const int4*)(col + s);
        int nv = cnt >> 2;
        for (int i = tid; i < nv; i += SBT) {
            int4 r4 = r4p[i];
            int4 c4 = c4p[i];
            int p;
            p = atomicAdd(&h[r4.x >> 7], 1); ebuf[p] = ((unsigned)(r4.x & 127) << 17) | (unsigned)c4.x;
            p = atomicAdd(&h[r4.y >> 7], 1); ebuf[p] = ((unsigned)(r4.y & 127) << 17) | (unsigned)c4.y;
            p = atomicAdd(&h[r4.z >> 7], 1); ebuf[p] = ((unsigned)(r4.z & 127) << 17) | (unsigned)c4.z;
            p = atomicAdd(&h[r4.w >> 7], 1); ebuf[p] = ((unsigned)(r4.w & 127) << 17) | (unsigned)c4.w;
        }
        for (int i = (nv << 2) + tid; i < cnt; i += SBT) {
            int r = row[s + i], c = col[s + i];
            int p = atomicAdd(&h[r >> 7], 1);
            ebuf[p] = ((unsigned)(r & 127) << 17) | (unsigned)c;
        }
    }
    __syncthreads();
    // coalesced dump (uint4)
    {
        uint4* dst = (uint4*)(sorted + s);
        const uint4* src = (const uint4*)ebuf;
        int nv = cnt >> 2;
        for (int i = tid; i < nv; i += SBT) dst[i] = src[i];
        for (int i = (nv << 2) + tid; i < cnt; i += SBT) sorted[s + i] = ebuf[i];
    }
}

// ---------------- Kernel 2: per-bucket two-pass node sort + pair-accumulate + Cholesky ----
// 256 threads handle G=512 runs: thread t owns chunks t and t+256 (2x MLP in both passes).
__global__ __launch_bounds__(256) void k_node3(const float2* __restrict__ pos,
                                               const unsigned int* __restrict__ sorted,
                                               const int* __restrict__ table,
                                               float* __restrict__ rec,
                                               int nN, int CE, int NB) {
    __shared__ unsigned int ebuf[CAP];   // node-sorted cols
    __shared__ int cnt[BN];
    __shared__ int off[BN + 1];
    __shared__ int cur[BN];
    __shared__ int goff0[G], glen[G];
    __shared__ int wt2[2];
    const int b = blockIdx.x, tid = threadIdx.x;
    const int tB = tid + 256;

    int offA0 = table[(size_t)b * G + tid];
    int offA1 = table[(size_t)(b + 1) * G + tid];
    int offB0 = table[(size_t)b * G + tB];
    int offB1 = table[(size_t)(b + 1) * G + tB];
    int lenA = offA1 - offA0;
    int lenB = offB1 - offB0;
    goff0[tid] = offA0; glen[tid] = lenA;
    goff0[tB] = offB0;  glen[tB] = lenB;
    if (tid < BN) cnt[tid] = 0;
    __syncthreads();

    // pass 1: count per local node (two independent run walks)
    const int gbaseA = tid * CE + offA0;
    const int gbaseB = tB * CE + offB0;
    {
        int j = 0;
        int lmin = min(lenA, lenB);
        for (; j < lmin; ++j) {
            unsigned va = sorted[gbaseA + j];
            unsigned vb = sorted[gbaseB + j];
            atomicAdd(&cnt[va >> 17], 1);
            atomicAdd(&cnt[vb >> 17], 1);
        }
        for (; j < lenA; ++j) atomicAdd(&cnt[sorted[gbaseA + j] >> 17], 1);
        for (; j < lenB; ++j) atomicAdd(&cnt[sorted[gbaseB + j] >> 17], 1);
    }
    __syncthreads();
    // 2-wave shfl scan of cnt -> off (exclusive), off[BN] = total
    int sv = 0, sx = 0;
    if (tid < BN) {
        sv = cnt[tid];
        sx = sv;
        #pragma unroll
        for (int d = 1; d < 64; d <<= 1) {
            int u = __shfl_up(sx, d);
            if ((tid & 63) >= d) sx += u;
        }
        if ((tid & 63) == 63) wt2[tid >> 6] = sx;
    }
    __syncthreads();
    if (tid < BN) {
        int incl = sx + ((tid >> 6) ? wt2[0] : 0);
        off[tid] = incl - sv;
        cur[tid] = incl - sv;
        if (tid == BN - 1) off[BN] = incl;
    }
    __syncthreads();
    const int total = off[BN];

    const bool fits = (total <= CAP);
    if (fits) {
        // pass 2: re-read runs (L2/L3-warm), place col at final node-sorted slot
        int j = 0;
        int lmin = min(lenA, lenB);
        for (; j < lmin; ++j) {
            unsigned va = sorted[gbaseA + j];
            unsigned vb = sorted[gbaseB + j];
            int pa = atomicAdd(&cur[(int)(va >> 17)], 1);
            ebuf[pa] = va & 0x1FFFFu;
            int pb = atomicAdd(&cur[(int)(vb >> 17)], 1);
            ebuf[pb] = vb & 0x1FFFFu;
        }
        for (; j < lenA; ++j) {
            unsigned va = sorted[gbaseA + j];
            int pa = atomicAdd(&cur[(int)(va >> 17)], 1);
            ebuf[pa] = va & 0x1FFFFu;
        }
        for (; j < lenB; ++j) {
            unsigned vb = sorted[gbaseB + j];
            int pb = atomicAdd(&cur[(int)(vb >> 17)], 1);
            ebuf[pb] = vb & 0x1FFFFu;
        }
    }
    __syncthreads();

    // accumulate: 2 threads per node (parity split), shfl_xor combine
    const int node = tid >> 1;
    const int half = tid & 1;
    const int n = (b << 7) + node;
    float m[15];
    #pragma unroll
    for (int i = 0; i < 15; ++i) m[i] = 0.0f;
    float2 pr = make_float2(0.f, 0.f);
    if (n < nN) {
        pr = pos[n];
        if (fits) {
            int j0 = off[node], j1 = off[node + 1];
            for (int j = j0 + half; j < j1; j += 2) {
                float2 pc = pos[ebuf[j]];
                float x = pc.x - pr.x;
                float y = pc.y - pr.y;
                float xy = x * y, xx = x * x, yy = y * y;
                m[0]  += x * x;   m[1]  += x * y;   m[2]  += x * xy;  m[3]  += x * xx;  m[4]  += x * yy;
                m[5]  += y * y;   m[6]  += y * xy;  m[7]  += y * xx;  m[8]  += y * yy;
                m[9]  += xy * xy; m[10] += xy * xx; m[11] += xy * yy;
                m[12] += xx * xx; m[13] += xx * yy;
                m[14] += yy * yy;
            }
        } else {
            // overflow fallback (statistically never): walk all runs, filter by node
            for (int g2 = half; g2 < G; g2 += 2) {
                int base2 = g2 * CE + goff0[g2];
                for (int j = 0; j < glen[g2]; ++j) {
                    unsigned v = sorted[base2 + j];
                    if ((int)(v >> 17) == node) {
                        float2 pc = pos[v & 0x1FFFFu];
                        float x = pc.x - pr.x;
                        float y = pc.y - pr.y;
                        float xy = x * y, xx = x * x, yy = y * y;
                        m[0]  += x * x;   m[1]  += x * y;   m[2]  += x * xy;  m[3]  += x * xx;  m[4]  += x * yy;
                        m[5]  += y * y;   m[6]  += y * xy;  m[7]  += y * xx;  m[8]  += y * yy;
                        m[9]  += xy * xy; m[10] += xy * xx; m[11] += xy * yy;
                        m[12] += xx * xx; m[13] += xx * yy;
                        m[14] += yy * yy;
                    }
                }
            }
        }
    }
    #pragma unroll
    for (int i = 0; i < 15; ++i) m[i] += __shfl_xor(m[i], 1);

    if (half == 0 && n < nN) {
        double A[5][5];
        {
            int idx = 0;
            #pragma unroll
            for (int i = 0; i < 5; ++i) {
                #pragma unroll
                for (int j = i; j < 5; ++j) {
                    double vv = (double)m[idx++];
                    A[i][j] = vv;
                    A[j][i] = vv;
                }
            }
        }
        #pragma unroll
        for (int i = 0; i < 5; ++i) A[i][i] += RIDGE;

        #pragma unroll
        for (int k = 0; k < 5; ++k) {
            double d = A[k][k];
            d = sqrt(fmax(d, 1e-300));
            A[k][k] = d;
            double inv = 1.0 / d;
            #pragma unroll
            for (int i = k + 1; i < 5; ++i) A[i][k] *= inv;
            #pragma unroll
            for (int j = k + 1; j < 5; ++j) {
                #pragma unroll
                for (int i = j; i < 5; ++i) A[i][j] -= A[i][k] * A[j][k];
            }
        }
        double bb[5] = {0.0, 0.0, 0.0, 2.0, 2.0};
        double y[5];
        #pragma unroll
        for (int i = 0; i < 5; ++i) {
            double sv2 = bb[i];
            #pragma unroll
            for (int k = 0; k < 5; ++k) {
                if (k < i) sv2 -= A[i][k] * y[k];
            }
            y[i] = sv2 / A[i][i];
        }
        double xs[5];
        #pragma unroll
        for (int ii = 4; ii >= 0; --ii) {
            double sv2 = y[ii];
            #pragma unroll
            for (int k = 0; k < 5; ++k) {
                if (k > ii) sv2 -= A[k][ii] * xs[k];
            }
            xs[ii] = sv2 / A[ii][ii];
        }
        float4* rb = (float4*)(rec + (size_t)n * 8);
        rb[0] = make_float4((float)xs[0], (float)xs[1], (float)xs[2], (float)xs[3]);
        rb[1] = make_float4((float)xs[4], pr.x, pr.y, 0.0f);
    }
}

// ---------------- Kernel 3: per-edge weight, 1 edge/thread (max TLP), nt streams ----------------
__global__ __launch_bounds__(1024) void k_weights(const float2* __restrict__ pos,
                                                  const int* __restrict__ row,
                                                  const int* __restrict__ col,
                                                  const float* __restrict__ rec,
                                                  float* __restrict__ out,
                                                  int nE) {
    int e = blockIdx.x * blockDim.x + threadIdx.x;
    if (e >= nE) return;
    int r = __builtin_nontemporal_load(row + e);
    int c = __builtin_nontemporal_load(col + e);
    const float4* rb = (const float4*)(rec + (size_t)r * 8);
    float4 q0 = rb[0];               // C0..C3
    float4 q1 = rb[1];               // C4, pos_r.x, pos_r.y, pad
    float2 pc = pos[c];
    float x = pc.x - q1.y;
    float y = pc.y - q1.z;
    float w = q0.x * x + q0.y * y + q0.z * (x * y) + q0.w * (x * x) + q1.x * (y * y);
    w = fminf(fmaxf(w, -WLIM), WLIM);
    __builtin_nontemporal_store(w, out + e);
}

extern "C" void kernel_launch(void* const* d_in, const int* in_sizes, int n_in,
                              void* d_out, int out_size, void* d_ws, size_t ws_size,
                              hipStream_t stream) {
    const float2* pos = (const float2*)d_in[0];
    const int* ei = (const int*)d_in[1];
    const int nN = in_sizes[0] / 2;   // (N,2) f32
    const int nE = in_sizes[1] / 2;   // (2,E) int32
    const int* row = ei;
    const int* col = ei + nE;

    const int NB = (nN + BN - 1) >> 7;              // buckets of 128 nodes (782)
    const int CE = (((nE + G - 1) / G) + 3) & ~3;   // edges per chunk, multiple of 4 (6252)

    // ws layout: table[(NB+1)*G] | pad to 16B | rec[nN*8 floats]
    int* table = (int*)d_ws;
    size_t roff = (((size_t)(NB + 1) * G) + 3) & ~(size_t)3;
    float* rec = (float*)((int*)d_ws + roff);

    unsigned int* sorted = (unsigned int*)d_out;  // consumed by k_node3 before k_weights overwrites
    float* out = (float*)d_out;

    k_sort<<<G, SBT, 0, stream>>>(row, col, table, sorted, nE, CE, NB);
    k_node3<<<NB, 256, 0, stream>>>(pos, sorted, table, rec, nN, CE, NB);
    k_weights<<<(nE + 1023) / 1024, 1024, 0, stream>>>(pos, row, col, rec, out, nE);
}

// Round 14
// 85.077 us; speedup vs baseline: 1.3447x; 1.3447x over previous
//
#include <hip/hip_runtime.h>
#include <math.h>

constexpr float WLIM = 5000.0f;
constexpr double RIDGE = 1e-7;

#define G 256             // edge chunks (one block each in k_sort; one thread each in k_node3)
#define MAXNB 1024        // max buckets (nN up to 131072)
#define BN 128            // nodes per bucket
#define CAP 5120          // LDS edge capacity per bucket in k_node3 (mean 4096, +16 sigma)
#define EBUF_CAP 12544    // LDS edge capacity per chunk in k_sort

// ---------------- Kernel 1: fused per-chunk {histogram, wave-scan, counting sort, dump} ----
// NOTE (R13 lesson): G=256 keeps per-(chunk,bucket) runs at ~16 edges (~64B).
// Halving chunk size halves run length and quadruples line overfetch in k_node3
// (measured: FETCH 25->120MB, 20->63us). Do not raise G.
__global__ __launch_bounds__(1024) void k_sort(const int* __restrict__ row,
                                               const int* __restrict__ col,
                                               int* __restrict__ table,
                                               unsigned int* __restrict__ sorted,
                                               int nE, int CE, int NB) {
    __shared__ int h[MAXNB];            // histogram -> cursors
    __shared__ int wt[16];
    __shared__ unsigned int ebuf[EBUF_CAP];
    const int g = blockIdx.x, tid = threadIdx.x;
    const int lane = tid & 63, wid = tid >> 6;
    const int s = g * CE;
    const int e_end = min(s + CE, nE);
    const int cnt = e_end - s;
    const bool vec = ((CE & 3) == 0);   // chunk bases 16B-aligned

    for (int i = tid; i < MAXNB; i += 1024) h[i] = 0;
    __syncthreads();
    // pass 1: histogram (LDS int atomics), int4 loads
    if (vec) {
        const int4* r4p = (const int4*)(row + s);
        int nv = cnt >> 2;
        for (int i = tid; i < nv; i += 1024) {
            int4 r4 = r4p[i];
            atomicAdd(&h[r4.x >> 7], 1);
            atomicAdd(&h[r4.y >> 7], 1);
            atomicAdd(&h[r4.z >> 7], 1);
            atomicAdd(&h[r4.w >> 7], 1);
        }
        for (int i = (nv << 2) + tid; i < cnt; i += 1024)
            atomicAdd(&h[row[s + i] >> 7], 1);
    } else {
        for (int i = s + tid; i < e_end; i += 1024)
            atomicAdd(&h[row[i] >> 7], 1);
    }
    __syncthreads();
    // wave-shfl scan of h[0..1023] (2 barriers total)
    int v = h[tid];
    int x = v;
    #pragma unroll
    for (int d = 1; d < 64; d <<= 1) {
        int u = __shfl_up(x, d);
        if (lane >= d) x += u;
    }
    if (lane == 63) wt[wid] = x;
    __syncthreads();
    if (tid < 16) {
        int w = wt[tid];
        int xx = w;
        #pragma unroll
        for (int d = 1; d < 16; d <<= 1) {
            int u = __shfl_up(xx, d);
            if (tid >= d) xx += u;
        }
        wt[tid] = xx - w;               // exclusive wave offset
    }
    __syncthreads();
    int excl = (x - v) + wt[wid];
    if (tid < NB) {
        table[(size_t)tid * G + g] = excl;   // transposed write
        h[tid] = excl;                       // cursor
    }
    if (tid == 0) table[(size_t)NB * G + g] = cnt;
    __syncthreads();
    // pass 2: counting sort into LDS (int4 loads, L2-warm)
    if (vec) {
        const int4* r4p = (const int4*)(row + s);
        const int4* c4p = (const int4*)(col + s);
        int nv = cnt >> 2;
        for (int i = tid; i < nv; i += 1024) {
            int4 r4 = r4p[i];
            int4 c4 = c4p[i];
            int p;
            p = atomicAdd(&h[r4.x >> 7], 1); ebuf[p] = ((unsigned)(r4.x & 127) << 17) | (unsigned)c4.x;
            p = atomicAdd(&h[r4.y >> 7], 1); ebuf[p] = ((unsigned)(r4.y & 127) << 17) | (unsigned)c4.y;
            p = atomicAdd(&h[r4.z >> 7], 1); ebuf[p] = ((unsigned)(r4.z & 127) << 17) | (unsigned)c4.z;
            p = atomicAdd(&h[r4.w >> 7], 1); ebuf[p] = ((unsigned)(r4.w & 127) << 17) | (unsigned)c4.w;
        }
        for (int i = (nv << 2) + tid; i < cnt; i += 1024) {
            int r = row[s + i], c = col[s + i];
            int p = atomicAdd(&h[r >> 7], 1);
            ebuf[p] = ((unsigned)(r & 127) << 17) | (unsigned)c;
        }
    } else {
        for (int i = s + tid; i < e_end; i += 1024) {
            int r = row[i], c = col[i];
            int p = atomicAdd(&h[r >> 7], 1);
            ebuf[p] = ((unsigned)(r & 127) << 17) | (unsigned)c;
        }
    }
    __syncthreads();
    // coalesced dump (uint4)
    if (vec) {
        uint4* dst = (uint4*)(sorted + s);
        const uint4* src = (const uint4*)ebuf;
        int nv = cnt >> 2;
        for (int i = tid; i < nv; i += 1024) dst[i] = src[i];
        for (int i = (nv << 2) + tid; i < cnt; i += 1024) sorted[s + i] = ebuf[i];
    } else {
        for (int i = tid; i < cnt; i += 1024) sorted[s + i] = ebuf[i];
    }
}

// ---------------- Kernel 2: per-bucket two-pass node sort + pair-accumulate + Cholesky ----
__global__ __launch_bounds__(256) void k_node3(const float2* __restrict__ pos,
                                               const unsigned int* __restrict__ sorted,
                                               const int* __restrict__ table,
                                               float* __restrict__ rec,
                                               int nN, int CE, int NB) {
    __shared__ unsigned int ebuf[CAP];   // node-sorted cols
    __shared__ int cnt[BN];
    __shared__ int off[BN + 1];
    __shared__ int cur[BN];
    __shared__ int goff0[G], glen[G];
    __shared__ int wt2[2];
    const int b = blockIdx.x, tid = threadIdx.x;

    int off0 = table[(size_t)b * G + tid];
    int off1 = table[(size_t)(b + 1) * G + tid];
    int len = off1 - off0;
    goff0[tid] = off0; glen[tid] = len;
    if (tid < BN) cnt[tid] = 0;
    __syncthreads();

    // pass 1: count per local node
    const int gbase = tid * CE + off0;
    for (int j = 0; j < len; ++j)
        atomicAdd(&cnt[sorted[gbase + j] >> 17], 1);
    __syncthreads();
    // 2-wave shfl scan of cnt -> off (exclusive), off[BN] = total
    int sv = 0, sx = 0;
    if (tid < BN) {
        sv = cnt[tid];
        sx = sv;
        #pragma unroll
        for (int d = 1; d < 64; d <<= 1) {
            int u = __shfl_up(sx, d);
            if ((tid & 63) >= d) sx += u;
        }
        if ((tid & 63) == 63) wt2[tid >> 6] = sx;
    }
    __syncthreads();
    if (tid < BN) {
        int incl = sx + ((tid >> 6) ? wt2[0] : 0);
        off[tid] = incl - sv;
        cur[tid] = incl - sv;
        if (tid == BN - 1) off[BN] = incl;
    }
    __syncthreads();
    const int total = off[BN];

    const bool fits = (total <= CAP);
    if (fits) {
        for (int j = 0; j < len; ++j) {
            unsigned v = sorted[gbase + j];
            int p = atomicAdd(&cur[(int)(v >> 17)], 1);
            ebuf[p] = v & 0x1FFFFu;
        }
    }
    __syncthreads();

    // accumulate: 2 threads per node (parity split), shfl_xor combine
    const int node = tid >> 1;
    const int half = tid & 1;
    const int n = (b << 7) + node;
    float m[15];
    #pragma unroll
    for (int i = 0; i < 15; ++i) m[i] = 0.0f;
    float2 pr = make_float2(0.f, 0.f);
    if (n < nN) {
        pr = pos[n];
        if (fits) {
            int j0 = off[node], j1 = off[node + 1];
            for (int j = j0 + half; j < j1; j += 2) {
                float2 pc = pos[ebuf[j]];
                float x = pc.x - pr.x;
                float y = pc.y - pr.y;
                float xy = x * y, xx = x * x, yy = y * y;
                m[0]  += x * x;   m[1]  += x * y;   m[2]  += x * xy;  m[3]  += x * xx;  m[4]  += x * yy;
                m[5]  += y * y;   m[6]  += y * xy;  m[7]  += y * xx;  m[8]  += y * yy;
                m[9]  += xy * xy; m[10] += xy * xx; m[11] += xy * yy;
                m[12] += xx * xx; m[13] += xx * yy;
                m[14] += yy * yy;
            }
        } else {
            for (int g2 = half; g2 < G; g2 += 2) {
                int base2 = g2 * CE + goff0[g2];
                for (int j = 0; j < glen[g2]; ++j) {
                    unsigned v = sorted[base2 + j];
                    if ((int)(v >> 17) == node) {
                        float2 pc = pos[v & 0x1FFFFu];
                        float x = pc.x - pr.x;
                        float y = pc.y - pr.y;
                        float xy = x * y, xx = x * x, yy = y * y;
                        m[0]  += x * x;   m[1]  += x * y;   m[2]  += x * xy;  m[3]  += x * xx;  m[4]  += x * yy;
                        m[5]  += y * y;   m[6]  += y * xy;  m[7]  += y * xx;  m[8]  += y * yy;
                        m[9]  += xy * xy; m[10] += xy * xx; m[11] += xy * yy;
                        m[12] += xx * xx; m[13] += xx * yy;
                        m[14] += yy * yy;
                    }
                }
            }
        }
    }
    #pragma unroll
    for (int i = 0; i < 15; ++i) m[i] += __shfl_xor(m[i], 1);

    if (half == 0 && n < nN) {
        double A[5][5];
        {
            int idx = 0;
            #pragma unroll
            for (int i = 0; i < 5; ++i) {
                #pragma unroll
                for (int j = i; j < 5; ++j) {
                    double vv = (double)m[idx++];
                    A[i][j] = vv;
                    A[j][i] = vv;
                }
            }
        }
        #pragma unroll
        for (int i = 0; i < 5; ++i) A[i][i] += RIDGE;

        #pragma unroll
        for (int k = 0; k < 5; ++k) {
            double d = A[k][k];
            d = sqrt(fmax(d, 1e-300));
            A[k][k] = d;
            double inv = 1.0 / d;
            #pragma unroll
            for (int i = k + 1; i < 5; ++i) A[i][k] *= inv;
            #pragma unroll
            for (int j = k + 1; j < 5; ++j) {
                #pragma unroll
                for (int i = j; i < 5; ++i) A[i][j] -= A[i][k] * A[j][k];
            }
        }
        double bb[5] = {0.0, 0.0, 0.0, 2.0, 2.0};
        double y[5];
        #pragma unroll
        for (int i = 0; i < 5; ++i) {
            double sv2 = bb[i];
            #pragma unroll
            for (int k = 0; k < 5; ++k) {
                if (k < i) sv2 -= A[i][k] * y[k];
            }
            y[i] = sv2 / A[i][i];
        }
        double xs[5];
        #pragma unroll
        for (int ii = 4; ii >= 0; --ii) {
            double sv2 = y[ii];
            #pragma unroll
            for (int k = 0; k < 5; ++k) {
                if (k > ii) sv2 -= A[k][ii] * xs[k];
            }
            xs[ii] = sv2 / A[ii][ii];
        }
        float4* rb = (float4*)(rec + (size_t)n * 8);
        rb[0] = make_float4((float)xs[0], (float)xs[1], (float)xs[2], (float)xs[3]);
        rb[1] = make_float4((float)xs[4], pr.x, pr.y, 0.0f);
    }
}

// ---------------- Kernel 3: per-edge weight, 1 edge/thread (max TLP), nt streams ----------------
// MSHR-bound at 3 gather requests/edge (rec 2x16B + pos 8B); 1 edge/thread
// maximizes outstanding misses (R11: 4/thread serialized at 28 VGPR, -25%).
__global__ __launch_bounds__(256) void k_weights(const float2* __restrict__ pos,
                                                 const int* __restrict__ row,
                                                 const int* __restrict__ col,
                                                 const float* __restrict__ rec,
                                                 float* __restrict__ out,
                                                 int nE) {
    int e = blockIdx.x * blockDim.x + threadIdx.x;
    if (e >= nE) return;
    int r = __builtin_nontemporal_load(row + e);
    int c = __builtin_nontemporal_load(col + e);
    const float4* rb = (const float4*)(rec + (size_t)r * 8);
    float4 q0 = rb[0];               // C0..C3
    float4 q1 = rb[1];               // C4, pos_r.x, pos_r.y, pad
    float2 pc = pos[c];
    float x = pc.x - q1.y;
    float y = pc.y - q1.z;
    float w = q0.x * x + q0.y * y + q0.z * (x * y) + q0.w * (x * x) + q1.x * (y * y);
    w = fminf(fmaxf(w, -WLIM), WLIM);
    __builtin_nontemporal_store(w, out + e);
}

extern "C" void kernel_launch(void* const* d_in, const int* in_sizes, int n_in,
                              void* d_out, int out_size, void* d_ws, size_t ws_size,
                              hipStream_t stream) {
    const float2* pos = (const float2*)d_in[0];
    const int* ei = (const int*)d_in[1];
    const int nN = in_sizes[0] / 2;   // (N,2) f32
    const int nE = in_sizes[1] / 2;   // (2,E) int32
    const int* row = ei;
    const int* col = ei + nE;

    const int NB = (nN + BN - 1) >> 7;        // buckets of 128 nodes (782)
    const int CE = (nE + G - 1) / G;          // edges per chunk (12500 <= EBUF_CAP)

    // ws layout: table[(NB+1)*G] | pad to 16B | rec[nN*8 floats]
    int* table = (int*)d_ws;
    size_t roff = (((size_t)(NB + 1) * G) + 3) & ~(size_t)3;
    float* rec = (float*)((int*)d_ws + roff);

    unsigned int* sorted = (unsigned int*)d_out;  // consumed by k_node3 before k_weights overwrites
    float* out = (float*)d_out;

    k_sort<<<G, 1024, 0, stream>>>(row, col, table, sorted, nE, CE, NB);
    k_node3<<<NB, 256, 0, stream>>>(pos, sorted, table, rec, nN, CE, NB);
    k_weights<<<(nE + 255) / 256, 256, 0, stream>>>(pos, row, col, rec, out, nE);
}